// Round 22
// baseline (405.646 us; speedup 1.0000x reference)
//
#include <hip/hip_runtime.h>
#include <hip/hip_bf16.h>
#include <math.h>

#define SEQN 1536
#define NH 8
#define MROWS 6144      // BATCH*SEQ
#define NDIST 3071      // 2*SEQ-1

typedef __attribute__((ext_vector_type(8))) _Float16 f16x8;
typedef __attribute__((ext_vector_type(4))) _Float16 f16x4;
typedef __attribute__((ext_vector_type(4))) float f32x4;

#define MFMAH(a, b, c) __builtin_amdgcn_mfma_f32_16x16x32_f16(a, b, c, 0, 0, 0)

__device__ __forceinline__ void gl_lds16(const void* g, void* l) {
  __builtin_amdgcn_global_load_lds(
      (const __attribute__((address_space(1))) void*)g,
      (__attribute__((address_space(3))) void*)l, 16, 0, 0);
}

// ------------- fused prep: relk (192 blocks) + all weight converts (3840 blocks) -------------
// Uniform 256-thread job table. relk blocks first (heavier; scheduled earliest).
// relk-256: thread owns cols t and t+256; 16 d-rows per block; e_g max via
// 2-local-max + 16-lane butterfly; PR heads w (cols 0..255) and w+4 (cols 256..511).
__global__ __launch_bounds__(256) void prep_kernel(
    const float* __restrict__ Wrk, const float* __restrict__ pb,
    _Float16* __restrict__ rk, float* __restrict__ PR,
    const float* __restrict__ Wq, const float* __restrict__ Wk,
    const float* __restrict__ Wv, const float* __restrict__ Wo,
    const float* __restrict__ W1, const float* __restrict__ W2,
    _Float16* __restrict__ TQKV, _Float16* __restrict__ TO,
    _Float16* __restrict__ T1w, _Float16* __restrict__ T2w) {
  __shared__ float prow[16][192];
  __shared__ _Float16 tile[64 * 73];
  const int bid = blockIdx.x;
  const int t = threadIdx.x;
  if (bid < 192) {
    // ---- relk: pos features in LDS, Wrk streamed once per block ----
    const int d0 = bid * 16;
    {
      const int r = t >> 4;
      const int j0 = t & 15;
      const int row = d0 + r;
      float dist = (float)(row - (SEQN - 1));
      float adist = fabsf(dist);
      float sgn = (dist > 0.f) ? 1.f : (dist < 0.f ? -1.f : 0.f);
      const float max_range = 10.58496250072116f;  // log2(1536)
      float probs[2];
      #pragma unroll
      for (int half = 0; half < 2; ++half) {
        int j = j0 + half * 16;
        float hl = exp2f(3.0f + ((max_range - 3.0f) / 31.0f) * (float)j);
        float e_exp = expf(-0.6931471805599453f / hl * adist);
        float cw = exp2f((float)(j + 1)) - 1.0f;
        float e_cm = (cw > adist) ? 1.0f : 0.0f;
        float mean = 48.0f * (float)(j + 1);
        float tt = mean / 24.0f;
        float conc = tt * tt;
        float rate = mean / 576.0f;
        float log_unnorm = (conc - 1.0f) * logf(fmaxf(adist, 1e-20f)) - rate * adist;
        float log_norm = lgammaf(conc) - conc * logf(rate);
        probs[half] = expf(log_unnorm - log_norm) + 1e-8f;
        prow[r][j] = e_exp;
        prow[r][32 + j] = e_cm;
        prow[r][96 + j] = sgn * e_exp;
        prow[r][128 + j] = sgn * e_cm;
      }
      float mx = fmaxf(probs[0], probs[1]);
      #pragma unroll
      for (int off = 8; off >= 1; off >>= 1)
        mx = fmaxf(mx, __shfl_xor(mx, off));
      #pragma unroll
      for (int half = 0; half < 2; ++half) {
        int j = j0 + half * 16;
        float e_g = probs[half] / mx;
        prow[r][64 + j] = e_g;
        prow[r][160 + j] = sgn * e_g;
      }
    }
    __syncthreads();
    float acc0[16], acc1[16];
    #pragma unroll
    for (int r = 0; r < 16; ++r) { acc0[r] = 0.f; acc1[r] = 0.f; }
    #pragma unroll 2
    for (int kk = 0; kk < 192; ++kk) {
      float wv0 = Wrk[(size_t)kk * 512 + t];
      float wv1 = Wrk[(size_t)kk * 512 + t + 256];
      #pragma unroll
      for (int r = 0; r < 16; ++r) {
        acc0[r] = fmaf(prow[r][kk], wv0, acc0[r]);
        acc1[r] = fmaf(prow[r][kk], wv1, acc1[r]);
      }
    }
    #pragma unroll
    for (int r = 0; r < 16; ++r) {
      rk[(size_t)(d0 + r) * 512 + t] = (_Float16)acc0[r];
      rk[(size_t)(d0 + r) * 512 + t + 256] = (_Float16)acc1[r];
    }
    float pb0 = pb[t], pb1 = pb[t + 256];
    const int wv = t >> 6;
    #pragma unroll
    for (int r = 0; r < 16; ++r) {
      float pv0 = pb0 * acc0[r];
      float pv1 = pb1 * acc1[r];
      #pragma unroll
      for (int off = 32; off >= 1; off >>= 1) {
        pv0 += __shfl_xor(pv0, off);
        pv1 += __shfl_xor(pv1, off);
      }
      if ((t & 63) == 0 && (d0 + r) < NDIST) {
        PR[(size_t)wv * NDIST + d0 + r] = pv0;
        PR[(size_t)(wv + 4) * NDIST + d0 + r] = pv1;
      }
    }
  } else {
    // ---- convw: 64x64 transpose tiles; f16 LDS tile [64][73] ----
    int tj = bid - 192;
    const float* W;
    _Float16* T;
    int N, KD, roff = 0;
    float scale = 1.0f;
    if (tj < 192) {
      W = Wq; T = TQKV; N = 512; KD = 1536; scale = 0.125f;
    } else if (tj < 384) {
      tj -= 192; W = Wk; T = TQKV; N = 512; KD = 1536; roff = 512;
    } else if (tj < 960) {
      tj -= 384; W = Wv; T = TQKV; N = 1536; KD = 1536; roff = 1024;
    } else if (tj < 1536) {
      tj -= 960; W = Wo; T = TO; N = 1536; KD = 1536;
    } else if (tj < 2688) {
      tj -= 1536; W = W1; T = T1w; N = 3072; KD = 1536;
    } else {
      tj -= 2688; W = W2; T = T2w; N = 1536; KD = 3072;
    }
    const int nx = N >> 6;
    const int n0 = (tj % nx) * 64, k0 = (tj / nx) * 64;
    const int r = t >> 6;            // 0..3
    const int c = t & 63;            // 0..63
    #pragma unroll
    for (int p = 0; p < 16; ++p) {
      int rr = r + p * 4;            // local k
      tile[rr * 73 + c] = (_Float16)(W[(size_t)(k0 + rr) * N + n0 + c] * scale);
    }
    __syncthreads();
    #pragma unroll
    for (int p = 0; p < 16; ++p) {
      int rr = r + p * 4;            // local n
      T[(size_t)(roff + n0 + rr) * KD + k0 + c] = tile[c * 73 + rr];
    }
  }
}

// ------------- layernorm: fp32 in -> f16 plane out -------------
__global__ __launch_bounds__(256) void ln_kernel(
    const float* __restrict__ x, const float* __restrict__ g,
    const float* __restrict__ bta, _Float16* __restrict__ oh) {
  const int row = blockIdx.x;
  const int t = threadIdx.x;
  __shared__ float red[4];
  __shared__ float bc[2];
  const float4* xr = (const float4*)(x + (size_t)row * 1536);
  float4 v0 = xr[t];
  float4 v1 = make_float4(0.f, 0.f, 0.f, 0.f);
  if (t < 128) v1 = xr[256 + t];
  float s = v0.x + v0.y + v0.z + v0.w;
  if (t < 128) s += v1.x + v1.y + v1.z + v1.w;
  #pragma unroll
  for (int off = 32; off >= 1; off >>= 1) s += __shfl_xor(s, off);
  if ((t & 63) == 0) red[t >> 6] = s;
  __syncthreads();
  if (t == 0) bc[0] = (red[0] + red[1] + red[2] + red[3]) * (1.f / 1536.f);
  __syncthreads();
  const float mu = bc[0];
  float d, s2 = 0.f;
  d = v0.x - mu; s2 += d * d; d = v0.y - mu; s2 += d * d;
  d = v0.z - mu; s2 += d * d; d = v0.w - mu; s2 += d * d;
  if (t < 128) {
    d = v1.x - mu; s2 += d * d; d = v1.y - mu; s2 += d * d;
    d = v1.z - mu; s2 += d * d; d = v1.w - mu; s2 += d * d;
  }
  #pragma unroll
  for (int off = 32; off >= 1; off >>= 1) s2 += __shfl_xor(s2, off);
  if ((t & 63) == 0) red[t >> 6] = s2;
  __syncthreads();
  if (t == 0) bc[1] = (red[0] + red[1] + red[2] + red[3]) * (1.f / 1536.f);
  __syncthreads();
  const float inv = rsqrtf(bc[1] + 1e-5f);
  const float4* g4 = (const float4*)g;
  const float4* b4 = (const float4*)bta;
  float4 gg = g4[t], bb = b4[t];
  f16x4 hv;
  hv[0] = (_Float16)((v0.x - mu) * inv * gg.x + bb.x);
  hv[1] = (_Float16)((v0.y - mu) * inv * gg.y + bb.y);
  hv[2] = (_Float16)((v0.z - mu) * inv * gg.z + bb.z);
  hv[3] = (_Float16)((v0.w - mu) * inv * gg.w + bb.w);
  *(f16x4*)(oh + (size_t)row * 1536 + t * 4) = hv;
  if (t < 128) {
    gg = g4[256 + t]; bb = b4[256 + t];
    hv[0] = (_Float16)((v1.x - mu) * inv * gg.x + bb.x);
    hv[1] = (_Float16)((v1.y - mu) * inv * gg.y + bb.y);
    hv[2] = (_Float16)((v1.z - mu) * inv * gg.z + bb.z);
    hv[3] = (_Float16)((v1.w - mu) * inv * gg.w + bb.w);
    *(f16x4*)(oh + (size_t)row * 1536 + 1024 + t * 4) = hv;
  }
}

// ------------- layernorm: f16 in -> f16 plane out (ln2 over f16 residual) -------------
__global__ __launch_bounds__(256) void ln16_kernel(
    const _Float16* __restrict__ x, const float* __restrict__ g,
    const float* __restrict__ bta, _Float16* __restrict__ oh) {
  const int row = blockIdx.x;
  const int t = threadIdx.x;
  __shared__ float red[4];
  __shared__ float bc[2];
  const f16x4* xr = (const f16x4*)(x + (size_t)row * 1536);
  f16x4 h0 = xr[t];
  float4 v0 = make_float4((float)h0[0], (float)h0[1], (float)h0[2], (float)h0[3]);
  float4 v1 = make_float4(0.f, 0.f, 0.f, 0.f);
  if (t < 128) {
    f16x4 h1 = xr[256 + t];
    v1 = make_float4((float)h1[0], (float)h1[1], (float)h1[2], (float)h1[3]);
  }
  float s = v0.x + v0.y + v0.z + v0.w;
  if (t < 128) s += v1.x + v1.y + v1.z + v1.w;
  #pragma unroll
  for (int off = 32; off >= 1; off >>= 1) s += __shfl_xor(s, off);
  if ((t & 63) == 0) red[t >> 6] = s;
  __syncthreads();
  if (t == 0) bc[0] = (red[0] + red[1] + red[2] + red[3]) * (1.f / 1536.f);
  __syncthreads();
  const float mu = bc[0];
  float d, s2 = 0.f;
  d = v0.x - mu; s2 += d * d; d = v0.y - mu; s2 += d * d;
  d = v0.z - mu; s2 += d * d; d = v0.w - mu; s2 += d * d;
  if (t < 128) {
    d = v1.x - mu; s2 += d * d; d = v1.y - mu; s2 += d * d;
    d = v1.z - mu; s2 += d * d; d = v1.w - mu; s2 += d * d;
  }
  #pragma unroll
  for (int off = 32; off >= 1; off >>= 1) s2 += __shfl_xor(s2, off);
  if ((t & 63) == 0) red[t >> 6] = s2;
  __syncthreads();
  if (t == 0) bc[1] = (red[0] + red[1] + red[2] + red[3]) * (1.f / 1536.f);
  __syncthreads();
  const float inv = rsqrtf(bc[1] + 1e-5f);
  const float4* g4 = (const float4*)g;
  const float4* b4 = (const float4*)bta;
  float4 gg = g4[t], bb = b4[t];
  f16x4 hv;
  hv[0] = (_Float16)((v0.x - mu) * inv * gg.x + bb.x);
  hv[1] = (_Float16)((v0.y - mu) * inv * gg.y + bb.y);
  hv[2] = (_Float16)((v0.z - mu) * inv * gg.z + bb.z);
  hv[3] = (_Float16)((v0.w - mu) * inv * gg.w + bb.w);
  *(f16x4*)(oh + (size_t)row * 1536 + t * 4) = hv;
  if (t < 128) {
    gg = g4[256 + t]; bb = b4[256 + t];
    hv[0] = (_Float16)((v1.x - mu) * inv * gg.x + bb.x);
    hv[1] = (_Float16)((v1.y - mu) * inv * gg.y + bb.y);
    hv[2] = (_Float16)((v1.z - mu) * inv * gg.z + bb.z);
    hv[3] = (_Float16)((v1.w - mu) * inv * gg.w + bb.w);
    *(f16x4*)(oh + (size_t)row * 1536 + 1024 + t * 4) = hv;
  }
}

// ------------- fp16 MFMA GEMM, 128xBN tile, BK=64 -------------
// EPI: 2 = bias+relu -> f16; 3 = bias+fp32 res -> fp32; 5 = bias+fp32 res -> f16;
//      6 = bias+f16 res (via Kp ptr) -> fp32; 4 = QKV epilogue + fused CK reduce
template <int EPI, int BNJ, int MW>
__global__ __launch_bounds__(256, MW) void mgemm_kernel(
    const _Float16* __restrict__ A, const _Float16* __restrict__ B,
    float* __restrict__ C, _Float16* __restrict__ Ch,
    _Float16* __restrict__ Kp, _Float16* __restrict__ Vt, float* __restrict__ CKo,
    const float* __restrict__ bias, const float* __restrict__ res,
    int M, int N, int K) {
  constexpr int BN = BNJ * 32;                 // 96 / 128 / 192
  __shared__ _Float16 sm[8192 + BN * 64];      // A[128][64] @0, B[BN][64] @8192
  const int t = threadIdx.x;
  const int lane = t & 63;
  const int w = t >> 6;
  const int wm = w >> 1, wn = w & 1;
  const int slab = (M >> 7) >> 3;              // row-tiles per XCD (6 for M=6144)
  const int xcd = blockIdx.x & 7;
  const int r = blockIdx.x >> 3;
  const int yt = xcd * slab + (r % slab);
  const int xt = r / slab;
  const int m0 = yt * 128, n0 = xt * BN;

  f32x4 acc[4][BNJ];
  #pragma unroll
  for (int i = 0; i < 4; ++i)
    #pragma unroll
    for (int j = 0; j < BNJ; ++j) acc[i][j] = (f32x4){0.f, 0.f, 0.f, 0.f};

  const int srow = t >> 3;
  const int ssl = t & 7;
  const int ss = ssl ^ (srow & 7);
  const int lr = lane & 15;
  const int g = lane >> 4;
  const int kb = lr & 7;                       // fragment-row swizzle key

  for (int k0 = 0; k0 < K; k0 += 64) {
    #pragma unroll
    for (int p = 0; p < 4; ++p) {
      int row = srow + p * 32;
      gl_lds16(A + (size_t)(m0 + row) * K + k0 + ss * 8, &sm[row * 64 + ssl * 8]);
    }
    #pragma unroll
    for (int p = 0; p < BN / 32; ++p) {
      int row = srow + p * 32;
      gl_lds16(B + (size_t)(n0 + row) * K + k0 + ss * 8,
               &sm[8192 + row * 64 + ssl * 8]);
    }
    __syncthreads();
    #pragma unroll
    for (int h2 = 0; h2 < 2; ++h2) {
      const int ksl = ((h2 * 4 + g) ^ kb) * 8;
      f16x8 a[4], b[BNJ];
      #pragma unroll
      for (int i = 0; i < 4; ++i)
        a[i] = *(const f16x8*)(&sm[(wm * 64 + i * 16 + lr) * 64 + ksl]);
      #pragma unroll
      for (int j = 0; j < BNJ; ++j)
        b[j] = *(const f16x8*)(&sm[8192 + (wn * BNJ * 16 + j * 16 + lr) * 64 + ksl]);
      #pragma unroll
      for (int i = 0; i < 4; ++i)
        #pragma unroll
        for (int j = 0; j < BNJ; ++j)
          acc[i][j] = MFMAH(a[i], b[j], acc[i][j]);
    }
    __syncthreads();
  }

  const int lq = lane >> 4;
  #pragma unroll
  for (int i = 0; i < 4; ++i) {
    #pragma unroll
    for (int j = 0; j < BNJ; ++j) {
      const int c0 = n0 + wn * BNJ * 16 + j * 16;   // tile col base (uniform)
      const int col = c0 + lr;
      const int rbase = m0 + wm * 64 + i * 16 + lq * 4;
      if (EPI == 3) {
        #pragma unroll
        for (int q = 0; q < 4; ++q) {
          size_t o = (size_t)(rbase + q) * N + col;
          C[o] = acc[i][j][q] + bias[col] + res[o];
        }
      } else if (EPI == 5) {
        #pragma unroll
        for (int q = 0; q < 4; ++q) {
          size_t o = (size_t)(rbase + q) * N + col;
          Ch[o] = (_Float16)(acc[i][j][q] + bias[col] + res[o]);
        }
      } else if (EPI == 6) {
        #pragma unroll
        for (int q = 0; q < 4; ++q) {
          size_t o = (size_t)(rbase + q) * N + col;
          C[o] = acc[i][j][q] + bias[col] + (float)Kp[o];
        }
      } else if (EPI == 2) {
        #pragma unroll
        for (int q = 0; q < 4; ++q) {
          size_t o = (size_t)(rbase + q) * N + col;
          Ch[o] = (_Float16)fmaxf(acc[i][j][q] + bias[col], 0.f);
        }
      } else {  // EPI == 4: QKV split epilogue
        if (c0 < 512) {
          #pragma unroll
          for (int q = 0; q < 4; ++q)
            Ch[(size_t)(rbase + q) * 512 + col] = (_Float16)acc[i][j][q];
        } else if (c0 < 1024) {
          #pragma unroll
          for (int q = 0; q < 4; ++q)
            Kp[(size_t)(rbase + q) * 512 + (col - 512)] = (_Float16)acc[i][j][q];
        } else {
          int dv = col - 1024;
          int hd = dv / 192;
          int dvh = dv - hd * 192;
          int bb = rbase / 1536;
          int nloc = rbase - bb * 1536;
          f16x4 pk;
          pk[0] = (_Float16)acc[i][j][0];
          pk[1] = (_Float16)acc[i][j][1];
          pk[2] = (_Float16)acc[i][j][2];
          pk[3] = (_Float16)acc[i][j][3];
          *(f16x4*)(Vt + (((size_t)bb * 8 + hd) * 192 + dvh) * 1536 + nloc) = pk;
        }
      }
    }
  }

  // fused CK reduce (EPI==4, K-region waves only; wave holds one full head)
  if (EPI == 4) {
    const int cw0 = n0 + wn * 64;               // wave col base (BNJ==4)
    if (cw0 >= 512 && cw0 < 1024) {
      const int hh = (cw0 - 512) >> 6;
      float cbv[4];
      #pragma unroll
      for (int j = 0; j < 4; ++j) cbv[j] = bias[cw0 - 512 + j * 16 + lr];
      #pragma unroll
      for (int i = 0; i < 4; ++i)
        #pragma unroll
        for (int q = 0; q < 4; ++q) {
          float v = acc[i][0][q] * cbv[0] + acc[i][1][q] * cbv[1] +
                    acc[i][2][q] * cbv[2] + acc[i][3][q] * cbv[3];
          #pragma unroll
          for (int off = 8; off >= 1; off >>= 1) v += __shfl_xor(v, off);
          if (lr == 0)
            CKo[(size_t)(m0 + wm * 64 + i * 16 + lq * 4 + q) * 8 + hh] = v;
        }
    }
  }
}

// ------------- MFMA flash attention (fp16): chunk 32, ring-R, 1 barrier/chunk -------------
__global__ __launch_bounds__(256, 3) void attn_kernel(
    const _Float16* __restrict__ Qp, const _Float16* __restrict__ Kp,
    const _Float16* __restrict__ Vt, const _Float16* __restrict__ rk,
    const float* __restrict__ PR, const float* __restrict__ CK,
    _Float16* __restrict__ ao) {
  __shared__ _Float16 lds[26752];
  const int id = blockIdx.x;
  const int xcd = id & 7, s = id >> 3;    // XCD-chunked (b,h) mapping
  const int bh = xcd * 4 + s / 24;
  const int it = s % 24;
  const int b = bh >> 3, h = bh & 7;
  const int t = threadIdx.x;
  const int w = t >> 6;
  const int lane = t & 63;
  const int c15 = lane & 15, g = lane >> 4;
  const int swz = c15 & 7;                // K/R read swizzle (row&7 == c15&7)
  const int vsz = (c15 >> 1) & 3;         // V read swizzle ((row>>1)&3)
  const int qrow0 = it * 64 + w * 16;     // wave's 16 Q rows
  const int rrow0 = 48 - w * 16;          // wave's band offset within window
  const int R0 = 1472 - it * 64;          // absolute rel_k row of ring origin

  // staging lane geometry
  const int lr = lane >> 3, sl = lane & 7;
  const int ss = sl ^ lr;                           // K/R source slot
  const int ss2 = (lane & 3) ^ ((lane >> 3) & 3);   // V source slot

  // persistent Q fragment (A-operand: lane holds row c15, k = g*8..+8, 32+g*8..+8)
  f16x8 qh0, qh1;
  {
    size_t qo = ((size_t)(b * SEQN + qrow0 + c15)) * 512 + h * 64 + g * 8;
    qh0 = *(const f16x8*)(Qp + qo);
    qh1 = *(const f16x8*)(Qp + qo + 32);
  }
  f16x8 ones;
  #pragma unroll
  for (int i = 0; i < 8; ++i) ones[i] = (_Float16)1.0f;
  const float* PRrow = PR + (size_t)h * NDIST;
  const float* CKb2 = CK + (size_t)b * SEQN * 8 + h;

  f32x4 acc[13];                          // [12] = row-sum (softmax denominator)
  #pragma unroll
  for (int d = 0; d < 13; ++d) acc[d] = (f32x4){0.f, 0.f, 0.f, 0.f};
  float mrun[4];
  #pragma unroll
  for (int q = 0; q < 4; ++q) mrun[q] = -1e30f;

  #define STAGE_KV(J0, KB, VB)                                                   \
    do {                                                                         \
      size_t gk = ((size_t)(b * SEQN + (J0) + w * 8 + lr)) * 512 + h * 64 + ss * 8; \
      gl_lds16(Kp + gk, &lds[(KB) + w * 512]);                                   \
      _Pragma("unroll") for (int p = 0; p < 3; ++p) {                            \
        int rv = w * 48 + p * 16 + (lane >> 2);                                  \
        size_t gv = (((size_t)(b * 8 + h)) * 192 + rv) * SEQN + (J0) + ss2 * 8;  \
        gl_lds16(Vt + gv, &lds[(VB) + (w * 48 + p * 16) * 32]);                  \
      }                                                                          \
    } while (0)

  #define STAGE_R_PRO()                                                          \
    do {                                                                         \
      _Pragma("unroll") for (int p = 0; p < 4; ++p) {                            \
        int rr = w * 32 + p * 8 + lr;                                            \
        size_t gr = ((size_t)(R0 + rr)) * 512 + h * 64 + ss * 8;                 \
        gl_lds16(rk + gr, &lds[16384 + (w * 32 + p * 8) * 64]);                  \
      }                                                                          \
    } while (0)

  #define STAGE_R_INC(REL0)                                                      \
    do {                                                                         \
      int rr = (REL0) + w * 8 + lr;                                              \
      size_t gr = ((size_t)(R0 + rr)) * 512 + h * 64 + ss * 8;                   \
      gl_lds16(rk + gr, &lds[16384 + ((((REL0) + w * 8) & 127)) * 64]);          \
    } while (0)

  #define COMP_T(DST, ETOFF)                                                     \
    do {                                                                         \
      int relrow = (cc32 + rrow0 + (ETOFF) + c15) & 127;                         \
      f16x8 r0_ = *(const f16x8*)(&lds[16384 + relrow * 64 + (g ^ swz) * 8]);    \
      f16x8 r1_ = *(const f16x8*)(&lds[16384 + relrow * 64 + ((4 + g) ^ swz) * 8]); \
      f32x4 tt_ = (f32x4){0.f, 0.f, 0.f, 0.f};                                   \
      tt_ = MFMAH(qh0, r0_, tt_);                                                \
      tt_ = MFMAH(qh1, r1_, tt_);                                                \
      float prv_ = PRrow[dbase + (ETOFF) + c15];                                 \
      _Pragma("unroll") for (int q = 0; q < 4; ++q) tt_[q] += prv_;              \
      DST = tt_;                                                                 \
    } while (0)

  STAGE_KV(0, 0, 4096);
  STAGE_R_PRO();

  f32x4 T0, T1, T2;

  for (int c = 0; c < 48; ++c) {
    const int j0 = c * 32;
    const int cc32 = c * 32;
    const int cur = c & 1;
    const int KB = cur * 2048;
    const int VB = 4096 + cur * 6144;
    __syncthreads();  // A: staged data for chunk c visible; prior reads complete

    // prefetch next chunk's K/V + ring rows (all drain by next A)
    if (c < 47) {
      STAGE_KV(j0 + 32, (cur ^ 1) * 2048, 4096 + (cur ^ 1) * 6144);
      if (c >= 1) STAGE_R_INC(cc32 + 96);
    }

    const int dbase = 1520 + j0 - qrow0;
    // ---- T tiles: carry T0 from previous chunk's T2; compute T1, T2 ----
    __builtin_amdgcn_s_setprio(1);
    if (c == 0) {
      COMP_T(T0, 0);
    } else {
      T0 = T2;
    }
    COMP_T(T1, 16);
    COMP_T(T2, 32);
    // ---- S = Q @ K^T ----
    f32x4 S[2];
    #pragma unroll
    for (int st = 0; st < 2; ++st) {
      int rowK = st * 16 + c15;
      f16x8 kh0 = *(const f16x8*)(&lds[KB + rowK * 64 + (g ^ swz) * 8]);
      f16x8 kh1 = *(const f16x8*)(&lds[KB + rowK * 64 + ((4 + g) ^ swz) * 8]);
      f32x4 ssv = (f32x4){0.f, 0.f, 0.f, 0.f};
      ssv = MFMAH(qh0, kh0, ssv);
      ssv = MFMAH(qh1, kh1, ssv);
      S[st] = ssv;
    }
    __builtin_amdgcn_s_setprio(0);
    // ---- add CK + gathered rel logits (12 shuffles) ----
    float ck0 = CKb2[(size_t)(j0 + c15) * 8];
    float ck1 = CKb2[(size_t)(j0 + 16 + c15) * 8];
    #pragma unroll
    for (int q = 0; q < 4; ++q) {
      int eoff = c15 + 15 - 4 * g - q;     // in [0,30]
      int src = (lane & 48) | (eoff & 15);
      float t0v = __shfl(T0[q], src);
      float t1v = __shfl(T1[q], src);
      float t2v = __shfl(T2[q], src);
      bool lo = eoff < 16;
      S[0][q] += ck0 + (lo ? t0v : t1v);
      S[1][q] += ck1 + (lo ? t1v : t2v);
    }
    // ---- online softmax with lazy defer-max (T13: __any test on raw S) ----
    int need = 0;
    #pragma unroll
    for (int st = 0; st < 2; ++st)
      #pragma unroll
      for (int q = 0; q < 4; ++q) need |= (S[st][q] > mrun[q] + 8.0f) ? 1 : 0;
    if (__any(need)) {
      float mx[4];
      #pragma unroll
      for (int q = 0; q < 4; ++q) mx[q] = fmaxf(S[0][q], S[1][q]);
      #pragma unroll
      for (int off = 8; off >= 1; off >>= 1)
        #pragma unroll
        for (int q = 0; q < 4; ++q) mx[q] = fmaxf(mx[q], __shfl_xor(mx[q], off));
      #pragma unroll
      for (int q = 0; q < 4; ++q) {
        float mn = fmaxf(mrun[q], mx[q]);
        float al = __expf(mrun[q] - mn);
        mrun[q] = mn;
        #pragma unroll
        for (int d = 0; d < 13; ++d) acc[d][q] *= al;
      }
    }
    // ---- P = exp(S - m); Ps repack (wave-private; same-wave write->read) ----
    #pragma unroll
    for (int st = 0; st < 2; ++st)
      #pragma unroll
      for (int q = 0; q < 4; ++q)
        lds[24576 + (w * 16 + 4 * g + q) * 34 + st * 16 + c15] =
            (_Float16)__expf(S[st][q] - mrun[q]);

    // ---- PV: P[16][32] @ V^T fragments; ones-MFMA accumulates row sums ----
    f16x8 pf = *(const f16x8*)(&lds[24576 + (w * 16 + c15) * 34 + g * 8]);
    __builtin_amdgcn_s_setprio(1);
    #pragma unroll
    for (int d = 0; d < 12; ++d) {
      int rowV = d * 16 + c15;
      f16x8 vf = *(const f16x8*)(&lds[VB + rowV * 32 + (g ^ vsz) * 8]);
      acc[d] = MFMAH(pf, vf, acc[d]);
    }
    acc[12] = MFMAH(pf, ones, acc[12]);
    __builtin_amdgcn_s_setprio(0);
  }

  // ---- epilogue: out = acc / rowsum -> f16 plane ----
  float rinv[4];
  #pragma unroll
  for (int q = 0; q < 4; ++q) rinv[q] = 1.0f / acc[12][q];
  #pragma unroll
  for (int d = 0; d < 12; ++d) {
    int col = h * 192 + d * 16 + c15;
    #pragma unroll
    for (int q = 0; q < 4; ++q) {
      size_t row = (size_t)(b * SEQN + qrow0 + 4 * g + q);
      ao[row * 1536 + col] = (_Float16)(acc[d][q] * rinv[q]);
    }
  }
  #undef STAGE_KV
  #undef STAGE_R_PRO
  #undef STAGE_R_INC
  #undef COMP_T
}

extern "C" void kernel_launch(void* const* d_in, const int* in_sizes, int n_in,
                              void* d_out, int out_size, void* d_ws, size_t ws_size,
                              hipStream_t stream) {
  (void)in_sizes; (void)n_in; (void)out_size; (void)ws_size;
  const float* x   = (const float*)d_in[0];
  const float* g1  = (const float*)d_in[1];
  const float* be1 = (const float*)d_in[2];
  const float* Wq  = (const float*)d_in[3];
  const float* Wk  = (const float*)d_in[4];
  const float* Wv  = (const float*)d_in[5];
  const float* Wo  = (const float*)d_in[6];
  const float* bo  = (const float*)d_in[7];
  const float* Wrk = (const float*)d_in[8];
  const float* cb  = (const float*)d_in[9];
  const float* pb  = (const float*)d_in[10];
  const float* g2  = (const float*)d_in[11];
  const float* be2 = (const float*)d_in[12];
  const float* W1  = (const float*)d_in[13];
  const float* b1  = (const float*)d_in[14];
  const float* W2  = (const float*)d_in[15];
  const float* b2  = (const float*)d_in[16];
  float* out = (float*)d_out;

  char* B = (char*)d_ws;
  _Float16* rk    = (_Float16*)(B + 0);           //  3,145,728 (3072 rows x 512)
  float* PRb      = (float*)(B + 3145728);        //     98,304
  float* CKb      = (float*)(B + 3244032);        //    196,608
  _Float16* xn    = (_Float16*)(B + 3440640);     // 18,874,368
  _Float16* WbQKV = (_Float16*)(B + 22315008);    //  7,864,320 (2560 x 1536)
  _Float16* WbO   = (_Float16*)(B + 30179328);    //  4,718,592 (1536 x 1536)
  _Float16* Wb1   = (_Float16*)(B + 34897920);    //  9,437,184 (3072 x 1536)
  _Float16* Wb2   = (_Float16*)(B + 44335104);    //  9,437,184 (1536 x 3072)
  _Float16* Qp    = (_Float16*)(B + 53772288);    //  6,291,456
  _Float16* Kp    = (_Float16*)(B + 60063744);    //  6,291,456
  _Float16* Vtp   = (_Float16*)(B + 66355200);    // 18,874,368
  _Float16* ao    = (_Float16*)(B + 85229568);    // 18,874,368
  _Float16* x2h   = (_Float16*)(B + 104103936);   // 18,874,368 (f16 residual stream)
  _Float16* h1    = (_Float16*)(B + 53772288);    // 37,748,736 (overlays dead Qp/Kp/Vtp/ao-head)
                                                  // -> max end 122,978,304

  prep_kernel<<<4032, 256, 0, stream>>>(Wrk, pb, rk, PRb,
                                        Wq, Wk, Wv, Wo, W1, W2,
                                        WbQKV, WbO, Wb1, Wb2);
  ln_kernel<<<MROWS, 256, 0, stream>>>(x, g1, be1, xn);
  mgemm_kernel<4, 4, 4><<<960, 256, 0, stream>>>(
      xn, WbQKV, nullptr, Qp, Kp, Vtp, CKb, cb, nullptr, MROWS, 2560, 1536);
  attn_kernel<<<768, 256, 0, stream>>>(Qp, Kp, Vtp, rk, PRb, CKb, ao);
  mgemm_kernel<5, 3, 4><<<768, 256, 0, stream>>>(
      ao, WbO, nullptr, x2h, nullptr, nullptr, nullptr, bo, x, MROWS, 1536, 1536);
  ln16_kernel<<<MROWS, 256, 0, stream>>>(x2h, g2, be2, xn);
  mgemm_kernel<2, 6, 3><<<768, 256, 0, stream>>>(
      xn, Wb1, nullptr, h1, nullptr, nullptr, nullptr, b1, nullptr, MROWS, 3072, 1536);
  mgemm_kernel<6, 3, 4><<<768, 256, 0, stream>>>(
      h1, Wb2, out, nullptr, x2h, nullptr, nullptr, b2, nullptr, MROWS, 1536, 3072);
}

// Round 23
// 386.900 us; speedup vs baseline: 1.0485x; 1.0485x over previous
//
#include <hip/hip_runtime.h>
#include <hip/hip_bf16.h>
#include <math.h>

#define SEQN 1536
#define NH 8
#define MROWS 6144      // BATCH*SEQ
#define NDIST 3071      // 2*SEQ-1

typedef __attribute__((ext_vector_type(8))) _Float16 f16x8;
typedef __attribute__((ext_vector_type(4))) _Float16 f16x4;
typedef __attribute__((ext_vector_type(4))) float f32x4;

#define MFMAH(a, b, c) __builtin_amdgcn_mfma_f32_16x16x32_f16(a, b, c, 0, 0, 0)

__device__ __forceinline__ void gl_lds16(const void* g, void* l) {
  __builtin_amdgcn_global_load_lds(
      (const __attribute__((address_space(1))) void*)g,
      (__attribute__((address_space(3))) void*)l, 16, 0, 0);
}

// ------------- fused pos_embed + rel_k: rk[3072][512] f16; PR[h][d] -------------
__global__ __launch_bounds__(512) void relk_kernel(
    const float* __restrict__ Wrk, const float* __restrict__ pb,
    _Float16* __restrict__ rk, float* __restrict__ PR) {
  __shared__ float prow[16][192];
  const int d0 = blockIdx.x * 16;
  const int t = threadIdx.x;
  {
    const int r = t >> 5, j = t & 31;
    const int row = d0 + r;
    float dist = (float)(row - (SEQN - 1));
    float adist = fabsf(dist);
    float sgn = (dist > 0.f) ? 1.f : (dist < 0.f ? -1.f : 0.f);
    const float max_range = 10.58496250072116f;  // log2(1536)
    float hl = exp2f(3.0f + ((max_range - 3.0f) / 31.0f) * (float)j);
    float e_exp = expf(-0.6931471805599453f / hl * adist);
    float cw = exp2f((float)(j + 1)) - 1.0f;
    float e_cm = (cw > adist) ? 1.0f : 0.0f;
    float mean = 48.0f * (float)(j + 1);
    float tt = mean / 24.0f;
    float conc = tt * tt;
    float rate = mean / 576.0f;
    float log_unnorm = (conc - 1.0f) * logf(fmaxf(adist, 1e-20f)) - rate * adist;
    float log_norm = lgammaf(conc) - conc * logf(rate);
    float prob = expf(log_unnorm - log_norm) + 1e-8f;
    float mx = prob;
    #pragma unroll
    for (int off = 16; off >= 1; off >>= 1)
      mx = fmaxf(mx, __shfl_xor(mx, off, 32));
    float e_g = prob / mx;
    prow[r][j] = e_exp;            prow[r][32 + j] = e_cm;
    prow[r][64 + j] = e_g;         prow[r][96 + j] = sgn * e_exp;
    prow[r][128 + j] = sgn * e_cm; prow[r][160 + j] = sgn * e_g;
  }
  __syncthreads();
  float acc[16];
  #pragma unroll
  for (int r = 0; r < 16; ++r) acc[r] = 0.f;
  #pragma unroll 4
  for (int kk = 0; kk < 192; ++kk) {
    float wv = Wrk[(size_t)kk * 512 + t];
    #pragma unroll
    for (int r = 0; r < 16; ++r) acc[r] = fmaf(prow[r][kk], wv, acc[r]);
  }
  #pragma unroll
  for (int r = 0; r < 16; ++r)
    rk[(size_t)(d0 + r) * 512 + t] = (_Float16)acc[r];
  float pbv = pb[t];
  #pragma unroll
  for (int r = 0; r < 16; ++r) {
    float pv = pbv * acc[r];
    #pragma unroll
    for (int off = 32; off >= 1; off >>= 1) pv += __shfl_xor(pv, off);
    if ((t & 63) == 0 && (d0 + r) < NDIST)
      PR[(size_t)(t >> 6) * NDIST + d0 + r] = pv;
  }
}

// ------------- layernorm: fp32 in -> f16 plane out -------------
__global__ __launch_bounds__(256) void ln_kernel(
    const float* __restrict__ x, const float* __restrict__ g,
    const float* __restrict__ bta, _Float16* __restrict__ oh) {
  const int row = blockIdx.x;
  const int t = threadIdx.x;
  __shared__ float red[4];
  __shared__ float bc[2];
  const float4* xr = (const float4*)(x + (size_t)row * 1536);
  float4 v0 = xr[t];
  float4 v1 = make_float4(0.f, 0.f, 0.f, 0.f);
  if (t < 128) v1 = xr[256 + t];
  float s = v0.x + v0.y + v0.z + v0.w;
  if (t < 128) s += v1.x + v1.y + v1.z + v1.w;
  #pragma unroll
  for (int off = 32; off >= 1; off >>= 1) s += __shfl_xor(s, off);
  if ((t & 63) == 0) red[t >> 6] = s;
  __syncthreads();
  if (t == 0) bc[0] = (red[0] + red[1] + red[2] + red[3]) * (1.f / 1536.f);
  __syncthreads();
  const float mu = bc[0];
  float d, s2 = 0.f;
  d = v0.x - mu; s2 += d * d; d = v0.y - mu; s2 += d * d;
  d = v0.z - mu; s2 += d * d; d = v0.w - mu; s2 += d * d;
  if (t < 128) {
    d = v1.x - mu; s2 += d * d; d = v1.y - mu; s2 += d * d;
    d = v1.z - mu; s2 += d * d; d = v1.w - mu; s2 += d * d;
  }
  #pragma unroll
  for (int off = 32; off >= 1; off >>= 1) s2 += __shfl_xor(s2, off);
  if ((t & 63) == 0) red[t >> 6] = s2;
  __syncthreads();
  if (t == 0) bc[1] = (red[0] + red[1] + red[2] + red[3]) * (1.f / 1536.f);
  __syncthreads();
  const float inv = rsqrtf(bc[1] + 1e-5f);
  const float4* g4 = (const float4*)g;
  const float4* b4 = (const float4*)bta;
  float4 gg = g4[t], bb = b4[t];
  f16x4 hv;
  hv[0] = (_Float16)((v0.x - mu) * inv * gg.x + bb.x);
  hv[1] = (_Float16)((v0.y - mu) * inv * gg.y + bb.y);
  hv[2] = (_Float16)((v0.z - mu) * inv * gg.z + bb.z);
  hv[3] = (_Float16)((v0.w - mu) * inv * gg.w + bb.w);
  *(f16x4*)(oh + (size_t)row * 1536 + t * 4) = hv;
  if (t < 128) {
    gg = g4[256 + t]; bb = b4[256 + t];
    hv[0] = (_Float16)((v1.x - mu) * inv * gg.x + bb.x);
    hv[1] = (_Float16)((v1.y - mu) * inv * gg.y + bb.y);
    hv[2] = (_Float16)((v1.z - mu) * inv * gg.z + bb.z);
    hv[3] = (_Float16)((v1.w - mu) * inv * gg.w + bb.w);
    *(f16x4*)(oh + (size_t)row * 1536 + 1024 + t * 4) = hv;
  }
}

// ------------- layernorm: f16 in -> f16 plane out (ln2 over f16 residual) -------------
__global__ __launch_bounds__(256) void ln16_kernel(
    const _Float16* __restrict__ x, const float* __restrict__ g,
    const float* __restrict__ bta, _Float16* __restrict__ oh) {
  const int row = blockIdx.x;
  const int t = threadIdx.x;
  __shared__ float red[4];
  __shared__ float bc[2];
  const f16x4* xr = (const f16x4*)(x + (size_t)row * 1536);
  f16x4 h0 = xr[t];
  float4 v0 = make_float4((float)h0[0], (float)h0[1], (float)h0[2], (float)h0[3]);
  float4 v1 = make_float4(0.f, 0.f, 0.f, 0.f);
  if (t < 128) {
    f16x4 h1 = xr[256 + t];
    v1 = make_float4((float)h1[0], (float)h1[1], (float)h1[2], (float)h1[3]);
  }
  float s = v0.x + v0.y + v0.z + v0.w;
  if (t < 128) s += v1.x + v1.y + v1.z + v1.w;
  #pragma unroll
  for (int off = 32; off >= 1; off >>= 1) s += __shfl_xor(s, off);
  if ((t & 63) == 0) red[t >> 6] = s;
  __syncthreads();
  if (t == 0) bc[0] = (red[0] + red[1] + red[2] + red[3]) * (1.f / 1536.f);
  __syncthreads();
  const float mu = bc[0];
  float d, s2 = 0.f;
  d = v0.x - mu; s2 += d * d; d = v0.y - mu; s2 += d * d;
  d = v0.z - mu; s2 += d * d; d = v0.w - mu; s2 += d * d;
  if (t < 128) {
    d = v1.x - mu; s2 += d * d; d = v1.y - mu; s2 += d * d;
    d = v1.z - mu; s2 += d * d; d = v1.w - mu; s2 += d * d;
  }
  #pragma unroll
  for (int off = 32; off >= 1; off >>= 1) s2 += __shfl_xor(s2, off);
  if ((t & 63) == 0) red[t >> 6] = s2;
  __syncthreads();
  if (t == 0) bc[1] = (red[0] + red[1] + red[2] + red[3]) * (1.f / 1536.f);
  __syncthreads();
  const float inv = rsqrtf(bc[1] + 1e-5f);
  const float4* g4 = (const float4*)g;
  const float4* b4 = (const float4*)bta;
  float4 gg = g4[t], bb = b4[t];
  f16x4 hv;
  hv[0] = (_Float16)((v0.x - mu) * inv * gg.x + bb.x);
  hv[1] = (_Float16)((v0.y - mu) * inv * gg.y + bb.y);
  hv[2] = (_Float16)((v0.z - mu) * inv * gg.z + bb.z);
  hv[3] = (_Float16)((v0.w - mu) * inv * gg.w + bb.w);
  *(f16x4*)(oh + (size_t)row * 1536 + t * 4) = hv;
  if (t < 128) {
    gg = g4[256 + t]; bb = b4[256 + t];
    hv[0] = (_Float16)((v1.x - mu) * inv * gg.x + bb.x);
    hv[1] = (_Float16)((v1.y - mu) * inv * gg.y + bb.y);
    hv[2] = (_Float16)((v1.z - mu) * inv * gg.z + bb.z);
    hv[3] = (_Float16)((v1.w - mu) * inv * gg.w + bb.w);
    *(f16x4*)(oh + (size_t)row * 1536 + 1024 + t * 4) = hv;
  }
}

// ------------- fused weight convert: all 6 weights, 64x64 tiles, ONE dispatch -------------
// 3840 blocks x 256 threads; f16 LDS tile [64][73] (odd pad -> <=2-way conflicts, free).
__global__ __launch_bounds__(256) void convw_all_kernel(
    const float* __restrict__ Wq, const float* __restrict__ Wk,
    const float* __restrict__ Wv, const float* __restrict__ Wo,
    const float* __restrict__ W1, const float* __restrict__ W2,
    _Float16* __restrict__ TQKV, _Float16* __restrict__ TO,
    _Float16* __restrict__ T1w, _Float16* __restrict__ T2w) {
  __shared__ _Float16 tile[64 * 73];
  int tj = blockIdx.x;
  const float* W;
  _Float16* T;
  int N, KD, roff = 0;
  float scale = 1.0f;
  if (tj < 192) {
    W = Wq; T = TQKV; N = 512; KD = 1536; scale = 0.125f;
  } else if (tj < 384) {
    tj -= 192; W = Wk; T = TQKV; N = 512; KD = 1536; roff = 512;
  } else if (tj < 960) {
    tj -= 384; W = Wv; T = TQKV; N = 1536; KD = 1536; roff = 1024;
  } else if (tj < 1536) {
    tj -= 960; W = Wo; T = TO; N = 1536; KD = 1536;
  } else if (tj < 2688) {
    tj -= 1536; W = W1; T = T1w; N = 3072; KD = 1536;
  } else {
    tj -= 2688; W = W2; T = T2w; N = 1536; KD = 3072;
  }
  const int nx = N >> 6;
  const int n0 = (tj % nx) * 64, k0 = (tj / nx) * 64;
  const int t = threadIdx.x;
  const int r = t >> 6;            // 0..3
  const int c = t & 63;            // 0..63
  #pragma unroll
  for (int p = 0; p < 16; ++p) {
    int rr = r + p * 4;            // local k
    tile[rr * 73 + c] = (_Float16)(W[(size_t)(k0 + rr) * N + n0 + c] * scale);
  }
  __syncthreads();
  #pragma unroll
  for (int p = 0; p < 16; ++p) {
    int rr = r + p * 4;            // local n
    T[(size_t)(roff + n0 + rr) * KD + k0 + c] = tile[c * 73 + rr];
  }
}

// ------------- fp16 MFMA GEMM, 128xBN tile, BK=64 -------------
// EPI: 2 = bias+relu -> f16; 3 = bias+fp32 res -> fp32; 5 = bias+fp32 res -> f16;
//      6 = bias+f16 res (via Kp ptr) -> fp32; 4 = QKV epilogue + fused CK reduce
template <int EPI, int BNJ, int MW>
__global__ __launch_bounds__(256, MW) void mgemm_kernel(
    const _Float16* __restrict__ A, const _Float16* __restrict__ B,
    float* __restrict__ C, _Float16* __restrict__ Ch,
    _Float16* __restrict__ Kp, _Float16* __restrict__ Vt, float* __restrict__ CKo,
    const float* __restrict__ bias, const float* __restrict__ res,
    int M, int N, int K) {
  constexpr int BN = BNJ * 32;                 // 96 / 128 / 192
  __shared__ _Float16 sm[8192 + BN * 64];      // A[128][64] @0, B[BN][64] @8192
  const int t = threadIdx.x;
  const int lane = t & 63;
  const int w = t >> 6;
  const int wm = w >> 1, wn = w & 1;
  const int slab = (M >> 7) >> 3;              // row-tiles per XCD (6 for M=6144)
  const int xcd = blockIdx.x & 7;
  const int r = blockIdx.x >> 3;
  const int yt = xcd * slab + (r % slab);
  const int xt = r / slab;
  const int m0 = yt * 128, n0 = xt * BN;

  f32x4 acc[4][BNJ];
  #pragma unroll
  for (int i = 0; i < 4; ++i)
    #pragma unroll
    for (int j = 0; j < BNJ; ++j) acc[i][j] = (f32x4){0.f, 0.f, 0.f, 0.f};

  const int srow = t >> 3;
  const int ssl = t & 7;
  const int ss = ssl ^ (srow & 7);
  const int lr = lane & 15;
  const int g = lane >> 4;
  const int kb = lr & 7;                       // fragment-row swizzle key

  for (int k0 = 0; k0 < K; k0 += 64) {
    #pragma unroll
    for (int p = 0; p < 4; ++p) {
      int row = srow + p * 32;
      gl_lds16(A + (size_t)(m0 + row) * K + k0 + ss * 8, &sm[row * 64 + ssl * 8]);
    }
    #pragma unroll
    for (int p = 0; p < BN / 32; ++p) {
      int row = srow + p * 32;
      gl_lds16(B + (size_t)(n0 + row) * K + k0 + ss * 8,
               &sm[8192 + row * 64 + ssl * 8]);
    }
    __syncthreads();
    #pragma unroll
    for (int h2 = 0; h2 < 2; ++h2) {
      const int ksl = ((h2 * 4 + g) ^ kb) * 8;
      f16x8 a[4], b[BNJ];
      #pragma unroll
      for (int i = 0; i < 4; ++i)
        a[i] = *(const f16x8*)(&sm[(wm * 64 + i * 16 + lr) * 64 + ksl]);
      #pragma unroll
      for (int j = 0; j < BNJ; ++j)
        b[j] = *(const f16x8*)(&sm[8192 + (wn * BNJ * 16 + j * 16 + lr) * 64 + ksl]);
      #pragma unroll
      for (int i = 0; i < 4; ++i)
        #pragma unroll
        for (int j = 0; j < BNJ; ++j)
          acc[i][j] = MFMAH(a[i], b[j], acc[i][j]);
    }
    __syncthreads();
  }

  const int lq = lane >> 4;
  #pragma unroll
  for (int i = 0; i < 4; ++i) {
    #pragma unroll
    for (int j = 0; j < BNJ; ++j) {
      const int c0 = n0 + wn * BNJ * 16 + j * 16;   // tile col base (uniform)
      const int col = c0 + lr;
      const int rbase = m0 + wm * 64 + i * 16 + lq * 4;
      if (EPI == 3) {
        #pragma unroll
        for (int q = 0; q < 4; ++q) {
          size_t o = (size_t)(rbase + q) * N + col;
          C[o] = acc[i][j][q] + bias[col] + res[o];
        }
      } else if (EPI == 5) {
        #pragma unroll
        for (int q = 0; q < 4; ++q) {
          size_t o = (size_t)(rbase + q) * N + col;
          Ch[o] = (_Float16)(acc[i][j][q] + bias[col] + res[o]);
        }
      } else if (EPI == 6) {
        #pragma unroll
        for (int q = 0; q < 4; ++q) {
          size_t o = (size_t)(rbase + q) * N + col;
          C[o] = acc[i][j][q] + bias[col] + (float)Kp[o];
        }
      } else if (EPI == 2) {
        #pragma unroll
        for (int q = 0; q < 4; ++q) {
          size_t o = (size_t)(rbase + q) * N + col;
          Ch[o] = (_Float16)fmaxf(acc[i][j][q] + bias[col], 0.f);
        }
      } else {  // EPI == 4: QKV split epilogue
        if (c0 < 512) {
          #pragma unroll
          for (int q = 0; q < 4; ++q)
            Ch[(size_t)(rbase + q) * 512 + col] = (_Float16)acc[i][j][q];
        } else if (c0 < 1024) {
          #pragma unroll
          for (int q = 0; q < 4; ++q)
            Kp[(size_t)(rbase + q) * 512 + (col - 512)] = (_Float16)acc[i][j][q];
        } else {
          int dv = col - 1024;
          int hd = dv / 192;
          int dvh = dv - hd * 192;
          int bb = rbase / 1536;
          int nloc = rbase - bb * 1536;
          f16x4 pk;
          pk[0] = (_Float16)acc[i][j][0];
          pk[1] = (_Float16)acc[i][j][1];
          pk[2] = (_Float16)acc[i][j][2];
          pk[3] = (_Float16)acc[i][j][3];
          *(f16x4*)(Vt + (((size_t)bb * 8 + hd) * 192 + dvh) * 1536 + nloc) = pk;
        }
      }
    }
  }

  // fused CK reduce (EPI==4, K-region waves only; wave holds one full head)
  if (EPI == 4) {
    const int cw0 = n0 + wn * 64;               // wave col base (BNJ==4)
    if (cw0 >= 512 && cw0 < 1024) {
      const int hh = (cw0 - 512) >> 6;
      float cbv[4];
      #pragma unroll
      for (int j = 0; j < 4; ++j) cbv[j] = bias[cw0 - 512 + j * 16 + lr];
      #pragma unroll
      for (int i = 0; i < 4; ++i)
        #pragma unroll
        for (int q = 0; q < 4; ++q) {
          float v = acc[i][0][q] * cbv[0] + acc[i][1][q] * cbv[1] +
                    acc[i][2][q] * cbv[2] + acc[i][3][q] * cbv[3];
          #pragma unroll
          for (int off = 8; off >= 1; off >>= 1) v += __shfl_xor(v, off);
          if (lr == 0)
            CKo[(size_t)(m0 + wm * 64 + i * 16 + lq * 4 + q) * 8 + hh] = v;
        }
    }
  }
}

// ------------- MFMA flash attention (fp16): chunk 32, ring-R, 1 barrier/chunk -------------
__global__ __launch_bounds__(256, 3) void attn_kernel(
    const _Float16* __restrict__ Qp, const _Float16* __restrict__ Kp,
    const _Float16* __restrict__ Vt, const _Float16* __restrict__ rk,
    const float* __restrict__ PR, const float* __restrict__ CK,
    _Float16* __restrict__ ao) {
  __shared__ _Float16 lds[26752];
  const int id = blockIdx.x;
  const int xcd = id & 7, s = id >> 3;    // XCD-chunked (b,h) mapping
  const int bh = xcd * 4 + s / 24;
  const int it = s % 24;
  const int b = bh >> 3, h = bh & 7;
  const int t = threadIdx.x;
  const int w = t >> 6;
  const int lane = t & 63;
  const int c15 = lane & 15, g = lane >> 4;
  const int swz = c15 & 7;                // K/R read swizzle (row&7 == c15&7)
  const int vsz = (c15 >> 1) & 3;         // V read swizzle ((row>>1)&3)
  const int qrow0 = it * 64 + w * 16;     // wave's 16 Q rows
  const int rrow0 = 48 - w * 16;          // wave's band offset within window
  const int R0 = 1472 - it * 64;          // absolute rel_k row of ring origin

  // staging lane geometry
  const int lr = lane >> 3, sl = lane & 7;
  const int ss = sl ^ lr;                           // K/R source slot
  const int ss2 = (lane & 3) ^ ((lane >> 3) & 3);   // V source slot

  // persistent Q fragment (A-operand: lane holds row c15, k = g*8..+8, 32+g*8..+8)
  f16x8 qh0, qh1;
  {
    size_t qo = ((size_t)(b * SEQN + qrow0 + c15)) * 512 + h * 64 + g * 8;
    qh0 = *(const f16x8*)(Qp + qo);
    qh1 = *(const f16x8*)(Qp + qo + 32);
  }
  f16x8 ones;
  #pragma unroll
  for (int i = 0; i < 8; ++i) ones[i] = (_Float16)1.0f;
  const float* PRrow = PR + (size_t)h * NDIST;
  const float* CKb2 = CK + (size_t)b * SEQN * 8 + h;

  f32x4 acc[13];                          // [12] = row-sum (softmax denominator)
  #pragma unroll
  for (int d = 0; d < 13; ++d) acc[d] = (f32x4){0.f, 0.f, 0.f, 0.f};
  float mrun[4];
  #pragma unroll
  for (int q = 0; q < 4; ++q) mrun[q] = -1e30f;

  #define STAGE_KV(J0, KB, VB)                                                   \
    do {                                                                         \
      size_t gk = ((size_t)(b * SEQN + (J0) + w * 8 + lr)) * 512 + h * 64 + ss * 8; \
      gl_lds16(Kp + gk, &lds[(KB) + w * 512]);                                   \
      _Pragma("unroll") for (int p = 0; p < 3; ++p) {                            \
        int rv = w * 48 + p * 16 + (lane >> 2);                                  \
        size_t gv = (((size_t)(b * 8 + h)) * 192 + rv) * SEQN + (J0) + ss2 * 8;  \
        gl_lds16(Vt + gv, &lds[(VB) + (w * 48 + p * 16) * 32]);                  \
      }                                                                          \
    } while (0)

  #define STAGE_R_PRO()                                                          \
    do {                                                                         \
      _Pragma("unroll") for (int p = 0; p < 4; ++p) {                            \
        int rr = w * 32 + p * 8 + lr;                                            \
        size_t gr = ((size_t)(R0 + rr)) * 512 + h * 64 + ss * 8;                 \
        gl_lds16(rk + gr, &lds[16384 + (w * 32 + p * 8) * 64]);                  \
      }                                                                          \
    } while (0)

  #define STAGE_R_INC(REL0)                                                      \
    do {                                                                         \
      int rr = (REL0) + w * 8 + lr;                                              \
      size_t gr = ((size_t)(R0 + rr)) * 512 + h * 64 + ss * 8;                   \
      gl_lds16(rk + gr, &lds[16384 + ((((REL0) + w * 8) & 127)) * 64]);          \
    } while (0)

  #define COMP_T(DST, ETOFF)                                                     \
    do {                                                                         \
      int relrow = (cc32 + rrow0 + (ETOFF) + c15) & 127;                         \
      f16x8 r0_ = *(const f16x8*)(&lds[16384 + relrow * 64 + (g ^ swz) * 8]);    \
      f16x8 r1_ = *(const f16x8*)(&lds[16384 + relrow * 64 + ((4 + g) ^ swz) * 8]); \
      f32x4 tt_ = (f32x4){0.f, 0.f, 0.f, 0.f};                                   \
      tt_ = MFMAH(qh0, r0_, tt_);                                                \
      tt_ = MFMAH(qh1, r1_, tt_);                                                \
      float prv_ = PRrow[dbase + (ETOFF) + c15];                                 \
      _Pragma("unroll") for (int q = 0; q < 4; ++q) tt_[q] += prv_;              \
      DST = tt_;                                                                 \
    } while (0)

  STAGE_KV(0, 0, 4096);
  STAGE_R_PRO();

  f32x4 T0, T1, T2;

  for (int c = 0; c < 48; ++c) {
    const int j0 = c * 32;
    const int cc32 = c * 32;
    const int cur = c & 1;
    const int KB = cur * 2048;
    const int VB = 4096 + cur * 6144;
    __syncthreads();  // A: staged data for chunk c visible; prior reads complete

    // prefetch next chunk's K/V + ring rows (all drain by next A)
    if (c < 47) {
      STAGE_KV(j0 + 32, (cur ^ 1) * 2048, 4096 + (cur ^ 1) * 6144);
      if (c >= 1) STAGE_R_INC(cc32 + 96);
    }

    const int dbase = 1520 + j0 - qrow0;
    // ---- T tiles: carry T0 from previous chunk's T2; compute T1, T2 ----
    __builtin_amdgcn_s_setprio(1);
    if (c == 0) {
      COMP_T(T0, 0);
    } else {
      T0 = T2;
    }
    COMP_T(T1, 16);
    COMP_T(T2, 32);
    // ---- S = Q @ K^T ----
    f32x4 S[2];
    #pragma unroll
    for (int st = 0; st < 2; ++st) {
      int rowK = st * 16 + c15;
      f16x8 kh0 = *(const f16x8*)(&lds[KB + rowK * 64 + (g ^ swz) * 8]);
      f16x8 kh1 = *(const f16x8*)(&lds[KB + rowK * 64 + ((4 + g) ^ swz) * 8]);
      f32x4 ssv = (f32x4){0.f, 0.f, 0.f, 0.f};
      ssv = MFMAH(qh0, kh0, ssv);
      ssv = MFMAH(qh1, kh1, ssv);
      S[st] = ssv;
    }
    __builtin_amdgcn_s_setprio(0);
    // ---- add CK + gathered rel logits (12 shuffles) ----
    float ck0 = CKb2[(size_t)(j0 + c15) * 8];
    float ck1 = CKb2[(size_t)(j0 + 16 + c15) * 8];
    #pragma unroll
    for (int q = 0; q < 4; ++q) {
      int eoff = c15 + 15 - 4 * g - q;     // in [0,30]
      int src = (lane & 48) | (eoff & 15);
      float t0v = __shfl(T0[q], src);
      float t1v = __shfl(T1[q], src);
      float t2v = __shfl(T2[q], src);
      bool lo = eoff < 16;
      S[0][q] += ck0 + (lo ? t0v : t1v);
      S[1][q] += ck1 + (lo ? t1v : t2v);
    }
    // ---- online softmax with lazy defer-max (T13: __any test on raw S) ----
    int need = 0;
    #pragma unroll
    for (int st = 0; st < 2; ++st)
      #pragma unroll
      for (int q = 0; q < 4; ++q) need |= (S[st][q] > mrun[q] + 8.0f) ? 1 : 0;
    if (__any(need)) {
      float mx[4];
      #pragma unroll
      for (int q = 0; q < 4; ++q) mx[q] = fmaxf(S[0][q], S[1][q]);
      #pragma unroll
      for (int off = 8; off >= 1; off >>= 1)
        #pragma unroll
        for (int q = 0; q < 4; ++q) mx[q] = fmaxf(mx[q], __shfl_xor(mx[q], off));
      #pragma unroll
      for (int q = 0; q < 4; ++q) {
        float mn = fmaxf(mrun[q], mx[q]);
        float al = __expf(mrun[q] - mn);
        mrun[q] = mn;
        #pragma unroll
        for (int d = 0; d < 13; ++d) acc[d][q] *= al;
      }
    }
    // ---- P = exp(S - m); Ps repack (wave-private; same-wave write->read) ----
    #pragma unroll
    for (int st = 0; st < 2; ++st)
      #pragma unroll
      for (int q = 0; q < 4; ++q)
        lds[24576 + (w * 16 + 4 * g + q) * 34 + st * 16 + c15] =
            (_Float16)__expf(S[st][q] - mrun[q]);

    // ---- PV: P[16][32] @ V^T fragments; ones-MFMA accumulates row sums ----
    f16x8 pf = *(const f16x8*)(&lds[24576 + (w * 16 + c15) * 34 + g * 8]);
    __builtin_amdgcn_s_setprio(1);
    #pragma unroll
    for (int d = 0; d < 12; ++d) {
      int rowV = d * 16 + c15;
      f16x8 vf = *(const f16x8*)(&lds[VB + rowV * 32 + (g ^ vsz) * 8]);
      acc[d] = MFMAH(pf, vf, acc[d]);
    }
    acc[12] = MFMAH(pf, ones, acc[12]);
    __builtin_amdgcn_s_setprio(0);
  }

  // ---- epilogue: out = acc / rowsum -> f16 plane ----
  float rinv[4];
  #pragma unroll
  for (int q = 0; q < 4; ++q) rinv[q] = 1.0f / acc[12][q];
  #pragma unroll
  for (int d = 0; d < 12; ++d) {
    int col = h * 192 + d * 16 + c15;
    #pragma unroll
    for (int q = 0; q < 4; ++q) {
      size_t row = (size_t)(b * SEQN + qrow0 + 4 * g + q);
      ao[row * 1536 + col] = (_Float16)(acc[d][q] * rinv[q]);
    }
  }
  #undef STAGE_KV
  #undef STAGE_R_PRO
  #undef STAGE_R_INC
  #undef COMP_T
}

extern "C" void kernel_launch(void* const* d_in, const int* in_sizes, int n_in,
                              void* d_out, int out_size, void* d_ws, size_t ws_size,
                              hipStream_t stream) {
  (void)in_sizes; (void)n_in; (void)out_size; (void)ws_size;
  const float* x   = (const float*)d_in[0];
  const float* g1  = (const float*)d_in[1];
  const float* be1 = (const float*)d_in[2];
  const float* Wq  = (const float*)d_in[3];
  const float* Wk  = (const float*)d_in[4];
  const float* Wv  = (const float*)d_in[5];
  const float* Wo  = (const float*)d_in[6];
  const float* bo  = (const float*)d_in[7];
  const float* Wrk = (const float*)d_in[8];
  const float* cb  = (const float*)d_in[9];
  const float* pb  = (const float*)d_in[10];
  const float* g2  = (const float*)d_in[11];
  const float* be2 = (const float*)d_in[12];
  const float* W1  = (const float*)d_in[13];
  const float* b1  = (const float*)d_in[14];
  const float* W2  = (const float*)d_in[15];
  const float* b2  = (const float*)d_in[16];
  float* out = (float*)d_out;

  char* B = (char*)d_ws;
  _Float16* rk    = (_Float16*)(B + 0);           //  3,145,728 (3072 rows x 512)
  float* PRb      = (float*)(B + 3145728);        //     98,304
  float* CKb      = (float*)(B + 3244032);        //    196,608
  _Float16* xn    = (_Float16*)(B + 3440640);     // 18,874,368
  _Float16* WbQKV = (_Float16*)(B + 22315008);    //  7,864,320 (2560 x 1536)
  _Float16* WbO   = (_Float16*)(B + 30179328);    //  4,718,592 (1536 x 1536)
  _Float16* Wb1   = (_Float16*)(B + 34897920);    //  9,437,184 (3072 x 1536)
  _Float16* Wb2   = (_Float16*)(B + 44335104);    //  9,437,184 (1536 x 3072)
  _Float16* Qp    = (_Float16*)(B + 53772288);    //  6,291,456
  _Float16* Kp    = (_Float16*)(B + 60063744);    //  6,291,456
  _Float16* Vtp   = (_Float16*)(B + 66355200);    // 18,874,368
  _Float16* ao    = (_Float16*)(B + 85229568);    // 18,874,368
  _Float16* x2h   = (_Float16*)(B + 104103936);   // 18,874,368 (f16 residual stream)
  _Float16* h1    = (_Float16*)(B + 53772288);    // 37,748,736 (overlays dead Qp/Kp/Vtp/ao-head)
                                                  // -> max end 122,978,304

  relk_kernel<<<192, 512, 0, stream>>>(Wrk, pb, rk, PRb);
  convw_all_kernel<<<3840, 256, 0, stream>>>(Wq, Wk, Wv, Wo, W1, W2,
                                             WbQKV, WbO, Wb1, Wb2);
  ln_kernel<<<MROWS, 256, 0, stream>>>(x, g1, be1, xn);
  mgemm_kernel<4, 4, 4><<<960, 256, 0, stream>>>(
      xn, WbQKV, nullptr, Qp, Kp, Vtp, CKb, cb, nullptr, MROWS, 2560, 1536);
  attn_kernel<<<768, 256, 0, stream>>>(Qp, Kp, Vtp, rk, PRb, CKb, ao);
  mgemm_kernel<5, 3, 4><<<768, 256, 0, stream>>>(
      ao, WbO, nullptr, x2h, nullptr, nullptr, nullptr, bo, x, MROWS, 1536, 1536);
  ln16_kernel<<<MROWS, 256, 0, stream>>>(x2h, g2, be2, xn);
  mgemm_kernel<2, 6, 3><<<768, 256, 0, stream>>>(
      xn, Wb1, nullptr, h1, nullptr, nullptr, nullptr, b1, nullptr, MROWS, 3072, 1536);
  mgemm_kernel<6, 3, 4><<<768, 256, 0, stream>>>(
      h1, Wb2, out, nullptr, x2h, nullptr, nullptr, b2, nullptr, MROWS, 1536, 3072);
}